// Round 1
// baseline (983.904 us; speedup 1.0000x reference)
//
#include <hip/hip_runtime.h>
#include <math.h>

constexpr int cE = 8;
constexpr int cH = 1024;
constexpr int cF = 2816;
constexpr int cR = 256;
constexpr int cT = 2048;
constexpr int ROWS = cT * 2;   // total routed (token, expert) rows = T*K

// ---------------------------------------------------------------------------
// Shared 64x64-tile fp32 GEMM inner loop. 256 threads; each thread owns a 4x4
// micro-tile. A is accessed through a per-thread row pointer (enables both
// plain and gathered A). K must be a multiple of 16; n-tile always full.
// ---------------------------------------------------------------------------
__device__ __forceinline__ void mm_loop(
    const float* __restrict__ arow,            // this thread's A row (or null)
    const float* __restrict__ B, int ldb, int n0, int K,
    float (&acc)[4][4], float (&As)[16][64], float (&Bs)[16][64], int tid)
{
  const int ar = tid >> 2;            // 0..63  A-tile row
  const int ak = (tid & 3) << 2;      // 0,4,8,12  A-tile k (float4)
  const int bk = tid >> 4;            // 0..15  B-tile k
  const int bn = (tid & 15) << 2;     // 0..60  B-tile n (float4)
  const int tx = tid & 15, ty = tid >> 4;
  for (int k0 = 0; k0 < K; k0 += 16) {
    float4 av = make_float4(0.f, 0.f, 0.f, 0.f);
    if (arow) av = *reinterpret_cast<const float4*>(arow + k0 + ak);
    As[ak + 0][ar] = av.x;
    As[ak + 1][ar] = av.y;
    As[ak + 2][ar] = av.z;
    As[ak + 3][ar] = av.w;
    *reinterpret_cast<float4*>(&Bs[bk][bn]) =
        *reinterpret_cast<const float4*>(B + (long)(k0 + bk) * ldb + n0 + bn);
    __syncthreads();
#pragma unroll
    for (int kk = 0; kk < 16; ++kk) {
      float4 a4 = *reinterpret_cast<const float4*>(&As[kk][ty << 2]);
      float4 b4 = *reinterpret_cast<const float4*>(&Bs[kk][tx << 2]);
      acc[0][0] += a4.x * b4.x; acc[0][1] += a4.x * b4.y; acc[0][2] += a4.x * b4.z; acc[0][3] += a4.x * b4.w;
      acc[1][0] += a4.y * b4.x; acc[1][1] += a4.y * b4.y; acc[1][2] += a4.y * b4.z; acc[1][3] += a4.y * b4.w;
      acc[2][0] += a4.z * b4.x; acc[2][1] += a4.z * b4.y; acc[2][2] += a4.z * b4.z; acc[2][3] += a4.z * b4.w;
      acc[3][0] += a4.w * b4.x; acc[3][1] += a4.w * b4.y; acc[3][2] += a4.w * b4.z; acc[3][3] += a4.w * b4.w;
    }
    __syncthreads();
  }
}

// ---------------------------------------------------------------------------
// zero d_out (harness poisons it with 0xAA)
// ---------------------------------------------------------------------------
__global__ __launch_bounds__(256) void k_zero(float* __restrict__ p, int n4)
{
  int i = blockIdx.x * 256 + threadIdx.x;
  if (i < n4) reinterpret_cast<float4*>(p)[i] = make_float4(0.f, 0.f, 0.f, 0.f);
}

// ---------------------------------------------------------------------------
// gating: logits = x @ gate_w, top-2, renormalized weights
// ---------------------------------------------------------------------------
__global__ __launch_bounds__(256) void k_gating(
    const float* __restrict__ x, const float* __restrict__ gw,
    int* __restrict__ et, float* __restrict__ wt)
{
  __shared__ float gws[cH * cE];              // 32 KB
  const int tid = threadIdx.x;
  for (int i = tid; i < cH * cE; i += 256) gws[i] = gw[i];
  __syncthreads();
  const int t = blockIdx.x * 256 + tid;
  const float4* xr = reinterpret_cast<const float4*>(x + (long)t * cH);
  float l[cE];
#pragma unroll
  for (int e = 0; e < cE; ++e) l[e] = 0.f;
  for (int h4 = 0; h4 < cH / 4; ++h4) {
    float4 v = xr[h4];
    const float* g0 = &gws[(h4 * 4 + 0) * cE];
    const float* g1 = &gws[(h4 * 4 + 1) * cE];
    const float* g2 = &gws[(h4 * 4 + 2) * cE];
    const float* g3 = &gws[(h4 * 4 + 3) * cE];
#pragma unroll
    for (int e = 0; e < cE; ++e)
      l[e] += v.x * g0[e] + v.y * g1[e] + v.z * g2[e] + v.w * g3[e];
  }
  // top-2 (stable: strict > keeps lowest index on ties, matching lax.top_k)
  int i0 = 0; float m0 = l[0];
#pragma unroll
  for (int e = 1; e < cE; ++e) if (l[e] > m0) { m0 = l[e]; i0 = e; }
  int i1 = -1; float m1 = -1e30f;
#pragma unroll
  for (int e = 0; e < cE; ++e) if (e != i0 && l[e] > m1) { m1 = l[e]; i1 = e; }
  // softmax-then-renormalize over top2 == 1/(1+exp(l1-l0))
  float w0 = 1.f / (1.f + expf(m1 - m0));
  float w1 = 1.f - w0;
  et[t * 2 + 0] = i0;  et[t * 2 + 1] = i1;
  wt[t * 2 + 0] = w0;  wt[t * 2 + 1] = w1;
}

// ---------------------------------------------------------------------------
// build compact per-expert token lists (single block)
// ---------------------------------------------------------------------------
__global__ __launch_bounds__(256) void k_lists(
    const int* __restrict__ et, const float* __restrict__ wt,
    int* __restrict__ tok, float* __restrict__ wrow,
    int* __restrict__ cnt, int* __restrict__ off)
{
  __shared__ int c[cE], p[cE], o[cE];
  const int tid = threadIdx.x;
  if (tid < cE) { c[tid] = 0; p[tid] = 0; }
  __syncthreads();
  for (int i = tid; i < ROWS; i += 256) atomicAdd(&c[et[i]], 1);
  __syncthreads();
  if (tid == 0) {
    int s = 0;
    for (int e = 0; e < cE; ++e) { o[e] = s; s += c[e]; }
  }
  __syncthreads();
  for (int i = tid; i < ROWS; i += 256) {
    int e = et[i];
    int slot = atomicAdd(&p[e], 1);
    int row = o[e] + slot;
    tok[row] = i >> 1;
    wrow[row] = wt[i];
  }
  if (tid < cE) { cnt[tid] = c[tid]; off[tid] = o[tid]; }
}

// ---------------------------------------------------------------------------
// generic batched GEMM: C[e] = A[e] @ B[e]  (strides may be 0 for shared mats)
// grid = (N/64, ceil(M/64), E)
// ---------------------------------------------------------------------------
__global__ __launch_bounds__(256) void k_gemm_bat(
    const float* __restrict__ A, long sA, int lda,
    const float* __restrict__ B, long sB, int ldb,
    float* __restrict__ C, long sC, int ldc, int M, int K)
{
  __shared__ float As[16][64], Bs[16][64];
  const int e = blockIdx.z;
  A += (long)e * sA; B += (long)e * sB; C += (long)e * sC;
  const int m0 = blockIdx.y * 64, n0 = blockIdx.x * 64;
  const int tid = threadIdx.x;
  const int ar = tid >> 2;
  const float* arow = (m0 + ar < M) ? A + (long)(m0 + ar) * lda : nullptr;
  float acc[4][4] = {};
  mm_loop(arow, B, ldb, n0, K, acc, As, Bs, tid);
  const int tx = tid & 15, ty = tid >> 4;
#pragma unroll
  for (int i = 0; i < 4; ++i) {
    int m = m0 + (ty << 2) + i;
    if (m < M)
      *reinterpret_cast<float4*>(&C[(long)m * ldc + n0 + (tx << 2)]) =
          make_float4(acc[i][0], acc[i][1], acc[i][2], acc[i][3]);
  }
}

// ---------------------------------------------------------------------------
// t1g/t1u = gather(x) @ Ug2[e] / Uu2[e]   (K=H)   grid = (8, 32, E)
// n-tiles 0..3 -> gate, 4..7 -> up
// ---------------------------------------------------------------------------
__global__ __launch_bounds__(256) void k_t1(
    const float* __restrict__ x,
    const float* __restrict__ Ug2, const float* __restrict__ Uu2,
    float* __restrict__ t1g, float* __restrict__ t1u,
    const int* __restrict__ tok, const int* __restrict__ cnt,
    const int* __restrict__ off)
{
  __shared__ float As[16][64], Bs[16][64];
  const int e = blockIdx.z;
  const int c = cnt[e], o = off[e];
  const int m0 = blockIdx.y * 64;
  if (m0 >= c) return;
  int nt = blockIdx.x;
  const float* B; float* C;
  if (nt < 4) { B = Ug2 + (long)e * cH * cR; C = t1g; }
  else        { B = Uu2 + (long)e * cH * cR; C = t1u; nt -= 4; }
  const int n0 = nt * 64;
  const int tid = threadIdx.x;
  const int ar = tid >> 2;
  const float* arow = nullptr;
  if (m0 + ar < c) arow = x + (long)tok[o + m0 + ar] * cH;
  float acc[4][4] = {};
  mm_loop(arow, B, cR, n0, cH, acc, As, Bs, tid);
  const int tx = tid & 15, ty = tid >> 4;
#pragma unroll
  for (int i = 0; i < 4; ++i) {
    int m = m0 + (ty << 2) + i;
    if (m < c)
      *reinterpret_cast<float4*>(&C[(long)(o + m) * cR + n0 + (tx << 2)]) =
          make_float4(acc[i][0], acc[i][1], acc[i][2], acc[i][3]);
  }
}

// ---------------------------------------------------------------------------
// a = silu(t1g @ Vg[e]) * (t1u @ Vu[e])   (K=R, N=F)   grid = (44, 32, E)
// ---------------------------------------------------------------------------
__global__ __launch_bounds__(256) void k_act(
    const float* __restrict__ t1g, const float* __restrict__ t1u,
    const float* __restrict__ Vg, const float* __restrict__ Vu,
    float* __restrict__ a, const int* __restrict__ cnt,
    const int* __restrict__ off)
{
  __shared__ float As[16][64], Bs[16][64];
  const int e = blockIdx.z;
  const int c = cnt[e], o = off[e];
  const int m0 = blockIdx.y * 64;
  if (m0 >= c) return;
  const int n0 = blockIdx.x * 64;
  const int tid = threadIdx.x;
  const int ar = tid >> 2;
  const bool valid = (m0 + ar < c);
  const float* arow_g = valid ? t1g + (long)(o + m0 + ar) * cR : nullptr;
  const float* arow_u = valid ? t1u + (long)(o + m0 + ar) * cR : nullptr;
  float accg[4][4] = {}, accu[4][4] = {};
  mm_loop(arow_g, Vg + (long)e * cR * cF, cF, n0, cR, accg, As, Bs, tid);
  mm_loop(arow_u, Vu + (long)e * cR * cF, cF, n0, cR, accu, As, Bs, tid);
  const int tx = tid & 15, ty = tid >> 4;
#pragma unroll
  for (int i = 0; i < 4; ++i) {
    int m = m0 + (ty << 2) + i;
    if (m < c) {
      float4 v;
      float g0 = accg[i][0], g1 = accg[i][1], g2 = accg[i][2], g3 = accg[i][3];
      v.x = g0 / (1.f + expf(-g0)) * accu[i][0];
      v.y = g1 / (1.f + expf(-g1)) * accu[i][1];
      v.z = g2 / (1.f + expf(-g2)) * accu[i][2];
      v.w = g3 / (1.f + expf(-g3)) * accu[i][3];
      *reinterpret_cast<float4*>(&a[(long)(o + m) * cF + n0 + (tx << 2)]) = v;
    }
  }
}

// ---------------------------------------------------------------------------
// t3 = a @ Ud[e]    (K=F, N=R)   grid = (4, 32, E)
// ---------------------------------------------------------------------------
__global__ __launch_bounds__(256) void k_t3(
    const float* __restrict__ a, const float* __restrict__ Ud,
    float* __restrict__ t3, const int* __restrict__ cnt,
    const int* __restrict__ off)
{
  __shared__ float As[16][64], Bs[16][64];
  const int e = blockIdx.z;
  const int c = cnt[e], o = off[e];
  const int m0 = blockIdx.y * 64;
  if (m0 >= c) return;
  const int n0 = blockIdx.x * 64;
  const int tid = threadIdx.x;
  const int ar = tid >> 2;
  const float* arow = (m0 + ar < c) ? a + (long)(o + m0 + ar) * cF : nullptr;
  float acc[4][4] = {};
  mm_loop(arow, Ud + (long)e * cF * cR, cR, n0, cF, acc, As, Bs, tid);
  const int tx = tid & 15, ty = tid >> 4;
#pragma unroll
  for (int i = 0; i < 4; ++i) {
    int m = m0 + (ty << 2) + i;
    if (m < c)
      *reinterpret_cast<float4*>(&t3[(long)(o + m) * cR + n0 + (tx << 2)]) =
          make_float4(acc[i][0], acc[i][1], acc[i][2], acc[i][3]);
  }
}

// ---------------------------------------------------------------------------
// y = t3 @ Vd2[e]; out[tok] += w * y   (K=R, N=H)   grid = (16, 32, E)
// ---------------------------------------------------------------------------
__global__ __launch_bounds__(256) void k_y(
    const float* __restrict__ t3, const float* __restrict__ Vd2,
    float* __restrict__ out, const int* __restrict__ tok,
    const float* __restrict__ wrow, const int* __restrict__ cnt,
    const int* __restrict__ off)
{
  __shared__ float As[16][64], Bs[16][64];
  const int e = blockIdx.z;
  const int c = cnt[e], o = off[e];
  const int m0 = blockIdx.y * 64;
  if (m0 >= c) return;
  const int n0 = blockIdx.x * 64;
  const int tid = threadIdx.x;
  const int ar = tid >> 2;
  const float* arow = (m0 + ar < c) ? t3 + (long)(o + m0 + ar) * cR : nullptr;
  float acc[4][4] = {};
  mm_loop(arow, Vd2 + (long)e * cR * cH, cH, n0, cR, acc, As, Bs, tid);
  const int tx = tid & 15, ty = tid >> 4;
#pragma unroll
  for (int i = 0; i < 4; ++i) {
    int m = m0 + (ty << 2) + i;
    if (m < c) {
      int t = tok[o + m];
      float w = wrow[o + m];
      float* dst = &out[(long)t * cH + n0 + (tx << 2)];
      atomicAdd(&dst[0], w * acc[i][0]);
      atomicAdd(&dst[1], w * acc[i][1]);
      atomicAdd(&dst[2], w * acc[i][2]);
      atomicAdd(&dst[3], w * acc[i][3]);
    }
  }
}

// ---------------------------------------------------------------------------
extern "C" void kernel_launch(void* const* d_in, const int* in_sizes, int n_in,
                              void* d_out, int out_size, void* d_ws, size_t ws_size,
                              hipStream_t stream)
{
  const float* x  = (const float*)d_in[0];
  const float* gw = (const float*)d_in[1];
  const float* Ug = (const float*)d_in[2];
  const float* Cg = (const float*)d_in[3];
  const float* Vg = (const float*)d_in[4];
  const float* Uu = (const float*)d_in[5];
  const float* Cu = (const float*)d_in[6];
  const float* Vu = (const float*)d_in[7];
  const float* Ud = (const float*)d_in[8];
  const float* Cd = (const float*)d_in[9];
  const float* Vd = (const float*)d_in[10];
  float* out = (float*)d_out;

  // workspace layout (fp32); total ~80.1 MiB
  float* w   = (float*)d_ws;
  float* ug2 = w;  w += (long)cE * cH * cR;
  float* uu2 = w;  w += (long)cE * cH * cR;
  float* vd2 = w;  w += (long)cE * cR * cH;
  float* t1g = w;  w += (long)ROWS * cR;
  float* t1u = w;  w += (long)ROWS * cR;
  float* t3  = w;  w += (long)ROWS * cR;
  float* ab  = w;  w += (long)ROWS * cF;
  float* wt   = w; w += ROWS;
  float* wrow = w; w += ROWS;
  int* et  = (int*)w;  w += ROWS;
  int* tok = (int*)w;  w += ROWS;
  int* cnt = (int*)w;  w += cE;
  int* off = (int*)w;  w += cE;

  // 1. zero output (poisoned with 0xAA by harness)
  k_zero<<<dim3((out_size / 4 + 255) / 256), dim3(256), 0, stream>>>(out, out_size / 4);
  // 2. gating
  k_gating<<<dim3(cT / 256), dim3(256), 0, stream>>>(x, gw, et, wt);
  // 3. compact per-expert lists
  k_lists<<<dim3(1), dim3(256), 0, stream>>>(et, wt, tok, wrow, cnt, off);
  // 4. fold shared cores: Ug2 = Ug@Cg, Uu2 = Uu@Cu, Vd2 = Cd@Vd
  k_gemm_bat<<<dim3(cR / 64, cH / 64, cE), dim3(256), 0, stream>>>(
      Ug, (long)cH * cR, cR, Cg, 0, cR, ug2, (long)cH * cR, cR, cH, cR);
  k_gemm_bat<<<dim3(cR / 64, cH / 64, cE), dim3(256), 0, stream>>>(
      Uu, (long)cH * cR, cR, Cu, 0, cR, uu2, (long)cH * cR, cR, cH, cR);
  k_gemm_bat<<<dim3(cH / 64, cR / 64, cE), dim3(256), 0, stream>>>(
      Cd, 0, cR, Vd, (long)cR * cH, cH, vd2, (long)cR * cH, cH, cR, cR);
  // 5. t1 = gather(x) @ {Ug2, Uu2}
  k_t1<<<dim3(8, cT / 64, cE), dim3(256), 0, stream>>>(
      x, ug2, uu2, t1g, t1u, tok, cnt, off);
  // 6. a = silu(t1g@Vg) * (t1u@Vu)
  k_act<<<dim3(cF / 64, cT / 64, cE), dim3(256), 0, stream>>>(
      t1g, t1u, Vg, Vu, ab, cnt, off);
  // 7. t3 = a @ Ud
  k_t3<<<dim3(cR / 64, cT / 64, cE), dim3(256), 0, stream>>>(
      ab, Ud, t3, cnt, off);
  // 8. out[tok] += w * (t3 @ Vd2)
  k_y<<<dim3(cH / 64, cT / 64, cE), dim3(256), 0, stream>>>(
      t3, vd2, out, tok, wrow, cnt, off);
}

// Round 2
// 650.864 us; speedup vs baseline: 1.5117x; 1.5117x over previous
//
#include <hip/hip_runtime.h>
#include <math.h>

constexpr int cE = 8;
constexpr int cH = 1024;
constexpr int cF = 2816;
constexpr int cR = 256;
constexpr int cT = 2048;
constexpr int ROWS = cT * 2;   // total routed (token, expert) rows = T*K
constexpr int LDA = 40;        // padded LDS row stride in bf16 (2-way conflicts only)

using short8  = __attribute__((ext_vector_type(8))) short;
using float4v = __attribute__((ext_vector_type(4))) float;
#define MFMA16 __builtin_amdgcn_mfma_f32_16x16x32_bf16

__device__ __forceinline__ unsigned short f2bf(float f) {
  union { float f; unsigned u; } v; v.f = f;
  unsigned r = v.u + 0x7fffu + ((v.u >> 16) & 1u);   // RNE
  return (unsigned short)(r >> 16);
}

// pack 8 fp32 -> 8 bf16, single 16B store
__device__ __forceinline__ void store_bf8(unsigned short* dst, float4 a, float4 b) {
  union { unsigned short u[8]; uint4 v; } t;
  t.u[0] = f2bf(a.x); t.u[1] = f2bf(a.y); t.u[2] = f2bf(a.z); t.u[3] = f2bf(a.w);
  t.u[4] = f2bf(b.x); t.u[5] = f2bf(b.y); t.u[6] = f2bf(b.z); t.u[7] = f2bf(b.w);
  *reinterpret_cast<uint4*>(dst) = t.v;
}

// ---------------------------------------------------------------------------
// zero d_out (harness poisons it with 0xAA)
// ---------------------------------------------------------------------------
__global__ __launch_bounds__(256) void k_zero(float* __restrict__ p, int n4)
{
  int i = blockIdx.x * 256 + threadIdx.x;
  if (i < n4) reinterpret_cast<float4*>(p)[i] = make_float4(0.f, 0.f, 0.f, 0.f);
}

// ---------------------------------------------------------------------------
// gating: logits = x @ gate_w, top-2, renormalized weights (fp32, tiny)
// ---------------------------------------------------------------------------
__global__ __launch_bounds__(256) void k_gating(
    const float* __restrict__ x, const float* __restrict__ gw,
    int* __restrict__ et, float* __restrict__ wt)
{
  __shared__ float gws[cH * cE];
  const int tid = threadIdx.x;
  for (int i = tid; i < cH * cE; i += 256) gws[i] = gw[i];
  __syncthreads();
  const int t = blockIdx.x * 256 + tid;
  const float4* xr = reinterpret_cast<const float4*>(x + (long)t * cH);
  float l[cE];
#pragma unroll
  for (int e = 0; e < cE; ++e) l[e] = 0.f;
  for (int h4 = 0; h4 < cH / 4; ++h4) {
    float4 v = xr[h4];
    const float* g0 = &gws[(h4 * 4 + 0) * cE];
    const float* g1 = &gws[(h4 * 4 + 1) * cE];
    const float* g2 = &gws[(h4 * 4 + 2) * cE];
    const float* g3 = &gws[(h4 * 4 + 3) * cE];
#pragma unroll
    for (int e = 0; e < cE; ++e)
      l[e] += v.x * g0[e] + v.y * g1[e] + v.z * g2[e] + v.w * g3[e];
  }
  int i0 = 0; float m0 = l[0];
#pragma unroll
  for (int e = 1; e < cE; ++e) if (l[e] > m0) { m0 = l[e]; i0 = e; }
  int i1 = -1; float m1 = -1e30f;
#pragma unroll
  for (int e = 0; e < cE; ++e) if (e != i0 && l[e] > m1) { m1 = l[e]; i1 = e; }
  float w0 = 1.f / (1.f + expf(m1 - m0));
  et[t * 2 + 0] = i0;  et[t * 2 + 1] = i1;
  wt[t * 2 + 0] = w0;  wt[t * 2 + 1] = 1.f - w0;
}

// ---------------------------------------------------------------------------
// build compact per-expert token lists (single block)
// ---------------------------------------------------------------------------
__global__ __launch_bounds__(256) void k_lists(
    const int* __restrict__ et, const float* __restrict__ wt,
    int* __restrict__ tok, float* __restrict__ wrow,
    int* __restrict__ cnt, int* __restrict__ off)
{
  __shared__ int c[cE], p[cE], o[cE];
  const int tid = threadIdx.x;
  if (tid < cE) { c[tid] = 0; p[tid] = 0; }
  __syncthreads();
  for (int i = tid; i < ROWS; i += 256) atomicAdd(&c[et[i]], 1);
  __syncthreads();
  if (tid == 0) {
    int s = 0;
    for (int e = 0; e < cE; ++e) { o[e] = s; s += c[e]; }
  }
  __syncthreads();
  for (int i = tid; i < ROWS; i += 256) {
    int e = et[i];
    int slot = atomicAdd(&p[e], 1);
    int row = o[e] + slot;
    tok[row] = i >> 1;
    wrow[row] = wt[i];
  }
  if (tid < cE) { cnt[tid] = c[tid]; off[tid] = o[tid]; }
}

// ---------------------------------------------------------------------------
// fp32 64x64 tile GEMM loop (round-1 structure, used only for the tiny folds)
// ---------------------------------------------------------------------------
__device__ __forceinline__ void mm_loop(
    const float* __restrict__ arow,
    const float* __restrict__ B, int ldb, int n0, int K,
    float (&acc)[4][4], float (&As)[16][64], float (&Bs)[16][64], int tid)
{
  const int ar = tid >> 2;
  const int ak = (tid & 3) << 2;
  const int bk = tid >> 4;
  const int bn = (tid & 15) << 2;
  const int tx = tid & 15, ty = tid >> 4;
  for (int k0 = 0; k0 < K; k0 += 16) {
    float4 av = *reinterpret_cast<const float4*>(arow + k0 + ak);
    As[ak + 0][ar] = av.x;
    As[ak + 1][ar] = av.y;
    As[ak + 2][ar] = av.z;
    As[ak + 3][ar] = av.w;
    *reinterpret_cast<float4*>(&Bs[bk][bn]) =
        *reinterpret_cast<const float4*>(B + (long)(k0 + bk) * ldb + n0 + bn);
    __syncthreads();
#pragma unroll
    for (int kk = 0; kk < 16; ++kk) {
      float4 a4 = *reinterpret_cast<const float4*>(&As[kk][ty << 2]);
      float4 b4 = *reinterpret_cast<const float4*>(&Bs[kk][tx << 2]);
      acc[0][0] += a4.x * b4.x; acc[0][1] += a4.x * b4.y; acc[0][2] += a4.x * b4.z; acc[0][3] += a4.x * b4.w;
      acc[1][0] += a4.y * b4.x; acc[1][1] += a4.y * b4.y; acc[1][2] += a4.y * b4.z; acc[1][3] += a4.y * b4.w;
      acc[2][0] += a4.z * b4.x; acc[2][1] += a4.z * b4.y; acc[2][2] += a4.z * b4.z; acc[2][3] += a4.z * b4.w;
      acc[3][0] += a4.w * b4.x; acc[3][1] += a4.w * b4.y; acc[3][2] += a4.w * b4.z; acc[3][3] += a4.w * b4.w;
    }
    __syncthreads();
  }
}

// fold: C = A @ B (fp32), stored TRANSPOSED as bf16: Ct[n*ldct + m]
// grid = (N/64, M/64, E); M,N multiples of 64.
__global__ __launch_bounds__(256) void k_fold(
    const float* __restrict__ A, long sA, int lda,
    const float* __restrict__ B, long sB, int ldb,
    unsigned short* __restrict__ Ct, long sC, int ldct, int K)
{
  __shared__ float As[16][64], Bs[16][64];
  const int e = blockIdx.z;
  A += (long)e * sA; B += (long)e * sB; Ct += (long)e * sC;
  const int m0 = blockIdx.y * 64, n0 = blockIdx.x * 64;
  const int tid = threadIdx.x;
  const float* arow = A + (long)(m0 + (tid >> 2)) * lda;
  float acc[4][4] = {};
  mm_loop(arow, B, ldb, n0, K, acc, As, Bs, tid);
  const int tx = tid & 15, ty = tid >> 4;
#pragma unroll
  for (int i = 0; i < 4; ++i) {
    int m = m0 + (ty << 2) + i;
#pragma unroll
    for (int j = 0; j < 4; ++j) {
      int n = n0 + (tx << 2) + j;
      Ct[(long)n * ldct + m] = f2bf(acc[i][j]);
    }
  }
}

// ---------------------------------------------------------------------------
// transpose + fp32->bf16: in [P][Q] per expert -> out [Q][P] per expert
// grid = (Q/32, P/32, E), 256 threads
// ---------------------------------------------------------------------------
__global__ __launch_bounds__(256) void k_tconv(
    const float* __restrict__ in, unsigned short* __restrict__ out, int P, int Q)
{
  __shared__ float tile[32][33];
  const long es = (long)P * Q;
  const int e = blockIdx.z;
  in += e * es; out += e * es;
  const int c0 = blockIdx.x * 32, r0 = blockIdx.y * 32;
  const int tid = threadIdx.x;
  const int r = tid >> 3, c4 = (tid & 7) * 4;
  float4 v = *reinterpret_cast<const float4*>(in + (long)(r0 + r) * Q + c0 + c4);
  tile[r][c4 + 0] = v.x; tile[r][c4 + 1] = v.y;
  tile[r][c4 + 2] = v.z; tile[r][c4 + 3] = v.w;
  __syncthreads();
  const int cc = tid >> 3, rr4 = (tid & 7) * 4;
  ushort4 o;
  o.x = f2bf(tile[rr4 + 0][cc]);
  o.y = f2bf(tile[rr4 + 1][cc]);
  o.z = f2bf(tile[rr4 + 2][cc]);
  o.w = f2bf(tile[rr4 + 3][cc]);
  *reinterpret_cast<ushort4*>(out + (long)(c0 + cc) * P + r0 + rr4) = o;
}

// ---------------------------------------------------------------------------
// MFMA GEMM 1: t1 = gather(x_fp32) @ b1t^T   [rows x 512], K = 1024
// b1t: [E][512][1024] bf16 (N-major).  tile 128x64, 4 waves of 64x32.
// grid = (8, 16, E)
// ---------------------------------------------------------------------------
__global__ __launch_bounds__(256) void k_t1(
    const float* __restrict__ x, const unsigned short* __restrict__ b1t,
    unsigned short* __restrict__ t1, const int* __restrict__ tok,
    const int* __restrict__ cnt, const int* __restrict__ off)
{
  __shared__ __align__(16) unsigned short As[128 * LDA];
  __shared__ __align__(16) unsigned short Bs[64 * LDA];
  const int e = blockIdx.z, c = cnt[e], o = off[e];
  const int m0 = blockIdx.y * 128;
  if (m0 >= c) return;
  const int n0 = blockIdx.x * 64;
  const unsigned short* Bt = b1t + (long)e * 512 * 1024 + (long)n0 * 1024;
  const int tid = threadIdx.x;
  const int sr = tid >> 2, sk = (tid & 3) * 8;
  const float* arow0 = (m0 + sr < c)      ? x + (long)tok[o + m0 + sr] * cH      : nullptr;
  const float* arow1 = (m0 + 64 + sr < c) ? x + (long)tok[o + m0 + 64 + sr] * cH : nullptr;
  const int wid = tid >> 6, lane = tid & 63;
  const int wm = (wid >> 1) * 64, wn = (wid & 1) * 32;
  const int fr = lane & 15, fq = lane >> 4;
  float4v zf = {0.f, 0.f, 0.f, 0.f};
  float4v acc[4][2];
#pragma unroll
  for (int i = 0; i < 4; ++i) { acc[i][0] = zf; acc[i][1] = zf; }
  const float4 z4 = make_float4(0.f, 0.f, 0.f, 0.f);
  for (int k0 = 0; k0 < cH; k0 += 32) {
    float4 a0 = arow0 ? *reinterpret_cast<const float4*>(arow0 + k0 + sk) : z4;
    float4 a1 = arow0 ? *reinterpret_cast<const float4*>(arow0 + k0 + sk + 4) : z4;
    store_bf8(&As[sr * LDA + sk], a0, a1);
    float4 b0 = arow1 ? *reinterpret_cast<const float4*>(arow1 + k0 + sk) : z4;
    float4 b1 = arow1 ? *reinterpret_cast<const float4*>(arow1 + k0 + sk + 4) : z4;
    store_bf8(&As[(sr + 64) * LDA + sk], b0, b1);
    *reinterpret_cast<uint4*>(&Bs[sr * LDA + sk]) =
        *reinterpret_cast<const uint4*>(Bt + (long)sr * 1024 + k0 + sk);
    __syncthreads();
    short8 af[4], bf[2];
#pragma unroll
    for (int mi = 0; mi < 4; ++mi)
      af[mi] = *reinterpret_cast<const short8*>(&As[(wm + mi * 16 + fr) * LDA + fq * 8]);
#pragma unroll
    for (int nj = 0; nj < 2; ++nj)
      bf[nj] = *reinterpret_cast<const short8*>(&Bs[(wn + nj * 16 + fr) * LDA + fq * 8]);
#pragma unroll
    for (int mi = 0; mi < 4; ++mi)
#pragma unroll
      for (int nj = 0; nj < 2; ++nj)
        acc[mi][nj] = MFMA16(af[mi], bf[nj], acc[mi][nj], 0, 0, 0);
    __syncthreads();
  }
#pragma unroll
  for (int mi = 0; mi < 4; ++mi)
#pragma unroll
    for (int r = 0; r < 4; ++r) {
      int row = m0 + wm + mi * 16 + fq * 4 + r;
      if (row < c) {
#pragma unroll
        for (int nj = 0; nj < 2; ++nj)
          t1[(long)(o + row) * 512 + n0 + wn + nj * 16 + fr] = f2bf(acc[mi][nj][r]);
      }
    }
}

// ---------------------------------------------------------------------------
// MFMA GEMM 2 (dual): a = silu(t1g @ vgT^T) * (t1u @ vuT^T)  [rows x F], K=256
// vgT/vuT: [E][F][256] bf16.  tile 128x64.  grid = (44, 16, E)
// ---------------------------------------------------------------------------
__global__ __launch_bounds__(256) void k_act(
    const unsigned short* __restrict__ t1,
    const unsigned short* __restrict__ vgT, const unsigned short* __restrict__ vuT,
    unsigned short* __restrict__ a, const int* __restrict__ cnt,
    const int* __restrict__ off)
{
  __shared__ __align__(16) unsigned short Ag[128 * LDA], Au[128 * LDA];
  __shared__ __align__(16) unsigned short Bg[64 * LDA],  Bu[64 * LDA];
  const int e = blockIdx.z, c = cnt[e], o = off[e];
  const int m0 = blockIdx.y * 128;
  if (m0 >= c) return;
  const int n0 = blockIdx.x * 64;
  const unsigned short* Btg = vgT + (long)e * cF * 256 + (long)n0 * 256;
  const unsigned short* Btu = vuT + (long)e * cF * 256 + (long)n0 * 256;
  const int tid = threadIdx.x;
  const int sr = tid >> 2, sk = (tid & 3) * 8;
  const unsigned short* ar0 = (m0 + sr < c)      ? t1 + (long)(o + m0 + sr) * 512      : nullptr;
  const unsigned short* ar1 = (m0 + 64 + sr < c) ? t1 + (long)(o + m0 + 64 + sr) * 512 : nullptr;
  const int wid = tid >> 6, lane = tid & 63;
  const int wm = (wid >> 1) * 64, wn = (wid & 1) * 32;
  const int fr = lane & 15, fq = lane >> 4;
  float4v zf = {0.f, 0.f, 0.f, 0.f};
  float4v accg[4][2], accu[4][2];
#pragma unroll
  for (int i = 0; i < 4; ++i) { accg[i][0] = zf; accg[i][1] = zf; accu[i][0] = zf; accu[i][1] = zf; }
  const uint4 zu = make_uint4(0u, 0u, 0u, 0u);
  for (int k0 = 0; k0 < 256; k0 += 32) {
    *reinterpret_cast<uint4*>(&Ag[sr * LDA + sk]) =
        ar0 ? *reinterpret_cast<const uint4*>(ar0 + k0 + sk) : zu;
    *reinterpret_cast<uint4*>(&Au[sr * LDA + sk]) =
        ar0 ? *reinterpret_cast<const uint4*>(ar0 + 256 + k0 + sk) : zu;
    *reinterpret_cast<uint4*>(&Ag[(sr + 64) * LDA + sk]) =
        ar1 ? *reinterpret_cast<const uint4*>(ar1 + k0 + sk) : zu;
    *reinterpret_cast<uint4*>(&Au[(sr + 64) * LDA + sk]) =
        ar1 ? *reinterpret_cast<const uint4*>(ar1 + 256 + k0 + sk) : zu;
    *reinterpret_cast<uint4*>(&Bg[sr * LDA + sk]) =
        *reinterpret_cast<const uint4*>(Btg + (long)sr * 256 + k0 + sk);
    *reinterpret_cast<uint4*>(&Bu[sr * LDA + sk]) =
        *reinterpret_cast<const uint4*>(Btu + (long)sr * 256 + k0 + sk);
    __syncthreads();
    short8 ag[4], au[4], bg[2], bu[2];
#pragma unroll
    for (int mi = 0; mi < 4; ++mi) {
      ag[mi] = *reinterpret_cast<const short8*>(&Ag[(wm + mi * 16 + fr) * LDA + fq * 8]);
      au[mi] = *reinterpret_cast<const short8*>(&Au[(wm + mi * 16 + fr) * LDA + fq * 8]);
    }
#pragma unroll
    for (int nj = 0; nj < 2; ++nj) {
      bg[nj] = *reinterpret_cast<const short8*>(&Bg[(wn + nj * 16 + fr) * LDA + fq * 8]);
      bu[nj] = *reinterpret_cast<const short8*>(&Bu[(wn + nj * 16 + fr) * LDA + fq * 8]);
    }
#pragma unroll
    for (int mi = 0; mi < 4; ++mi)
#pragma unroll
      for (int nj = 0; nj < 2; ++nj) {
        accg[mi][nj] = MFMA16(ag[mi], bg[nj], accg[mi][nj], 0, 0, 0);
        accu[mi][nj] = MFMA16(au[mi], bu[nj], accu[mi][nj], 0, 0, 0);
      }
    __syncthreads();
  }
#pragma unroll
  for (int mi = 0; mi < 4; ++mi)
#pragma unroll
    for (int r = 0; r < 4; ++r) {
      int row = m0 + wm + mi * 16 + fq * 4 + r;
      if (row < c) {
#pragma unroll
        for (int nj = 0; nj < 2; ++nj) {
          float g = accg[mi][nj][r];
          float u = accu[mi][nj][r];
          float s = g / (1.f + expf(-g)) * u;
          a[(long)(o + row) * cF + n0 + wn + nj * 16 + fr] = f2bf(s);
        }
      }
    }
}

// ---------------------------------------------------------------------------
// MFMA GEMM 3: t3 = a @ udT^T   [rows x 256], K = 2816
// udT: [E][256][2816] bf16.  tile 64x64, 4 waves of 32x32.  grid = (4, 32, E)
// ---------------------------------------------------------------------------
__global__ __launch_bounds__(256) void k_t3(
    const unsigned short* __restrict__ a, const unsigned short* __restrict__ udT,
    unsigned short* __restrict__ t3, const int* __restrict__ cnt,
    const int* __restrict__ off)
{
  __shared__ __align__(16) unsigned short As[64 * LDA], Bs[64 * LDA];
  const int e = blockIdx.z, c = cnt[e], o = off[e];
  const int m0 = blockIdx.y * 64;
  if (m0 >= c) return;
  const int n0 = blockIdx.x * 64;
  const unsigned short* Bt = udT + (long)e * 256 * cF + (long)n0 * cF;
  const int tid = threadIdx.x;
  const int sr = tid >> 2, sk = (tid & 3) * 8;
  const unsigned short* arow = (m0 + sr < c) ? a + (long)(o + m0 + sr) * cF : nullptr;
  const int wid = tid >> 6, lane = tid & 63;
  const int wm = (wid >> 1) * 32, wn = (wid & 1) * 32;
  const int fr = lane & 15, fq = lane >> 4;
  float4v zf = {0.f, 0.f, 0.f, 0.f};
  float4v acc[2][2] = {{zf, zf}, {zf, zf}};
  const uint4 zu = make_uint4(0u, 0u, 0u, 0u);
  for (int k0 = 0; k0 < cF; k0 += 32) {
    *reinterpret_cast<uint4*>(&As[sr * LDA + sk]) =
        arow ? *reinterpret_cast<const uint4*>(arow + k0 + sk) : zu;
    *reinterpret_cast<uint4*>(&Bs[sr * LDA + sk]) =
        *reinterpret_cast<const uint4*>(Bt + (long)sr * cF + k0 + sk);
    __syncthreads();
    short8 af[2], bf[2];
#pragma unroll
    for (int mi = 0; mi < 2; ++mi)
      af[mi] = *reinterpret_cast<const short8*>(&As[(wm + mi * 16 + fr) * LDA + fq * 8]);
#pragma unroll
    for (int nj = 0; nj < 2; ++nj)
      bf[nj] = *reinterpret_cast<const short8*>(&Bs[(wn + nj * 16 + fr) * LDA + fq * 8]);
#pragma unroll
    for (int mi = 0; mi < 2; ++mi)
#pragma unroll
      for (int nj = 0; nj < 2; ++nj)
        acc[mi][nj] = MFMA16(af[mi], bf[nj], acc[mi][nj], 0, 0, 0);
    __syncthreads();
  }
#pragma unroll
  for (int mi = 0; mi < 2; ++mi)
#pragma unroll
    for (int r = 0; r < 4; ++r) {
      int row = m0 + wm + mi * 16 + fq * 4 + r;
      if (row < c) {
#pragma unroll
        for (int nj = 0; nj < 2; ++nj)
          t3[(long)(o + row) * 256 + n0 + wn + nj * 16 + fr] = f2bf(acc[mi][nj][r]);
      }
    }
}

// ---------------------------------------------------------------------------
// MFMA GEMM 4: out[tok] += w * (t3 @ vd2t^T)   [rows x 1024], K = 256
// vd2t: [E][1024][256] bf16.  tile 128x64.  grid = (16, 16, E)
// ---------------------------------------------------------------------------
__global__ __launch_bounds__(256) void k_y(
    const unsigned short* __restrict__ t3, const unsigned short* __restrict__ vd2t,
    float* __restrict__ out, const int* __restrict__ tok,
    const float* __restrict__ wrow, const int* __restrict__ cnt,
    const int* __restrict__ off)
{
  __shared__ __align__(16) unsigned short As[128 * LDA], Bs[64 * LDA];
  const int e = blockIdx.z, c = cnt[e], o = off[e];
  const int m0 = blockIdx.y * 128;
  if (m0 >= c) return;
  const int n0 = blockIdx.x * 64;
  const unsigned short* Bt = vd2t + (long)e * cH * 256 + (long)n0 * 256;
  const int tid = threadIdx.x;
  const int sr = tid >> 2, sk = (tid & 3) * 8;
  const unsigned short* ar0 = (m0 + sr < c)      ? t3 + (long)(o + m0 + sr) * 256      : nullptr;
  const unsigned short* ar1 = (m0 + 64 + sr < c) ? t3 + (long)(o + m0 + 64 + sr) * 256 : nullptr;
  const int wid = tid >> 6, lane = tid & 63;
  const int wm = (wid >> 1) * 64, wn = (wid & 1) * 32;
  const int fr = lane & 15, fq = lane >> 4;
  float4v zf = {0.f, 0.f, 0.f, 0.f};
  float4v acc[4][2];
#pragma unroll
  for (int i = 0; i < 4; ++i) { acc[i][0] = zf; acc[i][1] = zf; }
  const uint4 zu = make_uint4(0u, 0u, 0u, 0u);
  for (int k0 = 0; k0 < 256; k0 += 32) {
    *reinterpret_cast<uint4*>(&As[sr * LDA + sk]) =
        ar0 ? *reinterpret_cast<const uint4*>(ar0 + k0 + sk) : zu;
    *reinterpret_cast<uint4*>(&As[(sr + 64) * LDA + sk]) =
        ar1 ? *reinterpret_cast<const uint4*>(ar1 + k0 + sk) : zu;
    *reinterpret_cast<uint4*>(&Bs[sr * LDA + sk]) =
        *reinterpret_cast<const uint4*>(Bt + (long)sr * 256 + k0 + sk);
    __syncthreads();
    short8 af[4], bf[2];
#pragma unroll
    for (int mi = 0; mi < 4; ++mi)
      af[mi] = *reinterpret_cast<const short8*>(&As[(wm + mi * 16 + fr) * LDA + fq * 8]);
#pragma unroll
    for (int nj = 0; nj < 2; ++nj)
      bf[nj] = *reinterpret_cast<const short8*>(&Bs[(wn + nj * 16 + fr) * LDA + fq * 8]);
#pragma unroll
    for (int mi = 0; mi < 4; ++mi)
#pragma unroll
      for (int nj = 0; nj < 2; ++nj)
        acc[mi][nj] = MFMA16(af[mi], bf[nj], acc[mi][nj], 0, 0, 0);
    __syncthreads();
  }
#pragma unroll
  for (int mi = 0; mi < 4; ++mi)
#pragma unroll
    for (int r = 0; r < 4; ++r) {
      int row = m0 + wm + mi * 16 + fq * 4 + r;
      if (row < c) {
        int t = tok[o + row];
        float w = wrow[o + row];
        float* dst = out + (long)t * cH + n0 + wn;
#pragma unroll
        for (int nj = 0; nj < 2; ++nj)
          atomicAdd(dst + nj * 16 + fr, w * acc[mi][nj][r]);
      }
    }
}

// ---------------------------------------------------------------------------
extern "C" void kernel_launch(void* const* d_in, const int* in_sizes, int n_in,
                              void* d_out, int out_size, void* d_ws, size_t ws_size,
                              hipStream_t stream)
{
  const float* x  = (const float*)d_in[0];
  const float* gw = (const float*)d_in[1];
  const float* Ug = (const float*)d_in[2];
  const float* Cg = (const float*)d_in[3];
  const float* Vg = (const float*)d_in[4];
  const float* Uu = (const float*)d_in[5];
  const float* Cu = (const float*)d_in[6];
  const float* Vu = (const float*)d_in[7];
  const float* Ud = (const float*)d_in[8];
  const float* Cd = (const float*)d_in[9];
  const float* Vd = (const float*)d_in[10];
  float* out = (float*)d_out;

  // workspace layout: ~76.6 MiB total
  char* w = (char*)d_ws;
  unsigned short* b1t  = (unsigned short*)w; w += (long)cE * 512 * 1024 * 2;   // 8.39 MB
  unsigned short* vd2t = (unsigned short*)w; w += (long)cE * cH * 256 * 2;     // 4.19 MB
  unsigned short* vgT  = (unsigned short*)w; w += (long)cE * cF * 256 * 2;     // 11.53 MB
  unsigned short* vuT  = (unsigned short*)w; w += (long)cE * cF * 256 * 2;     // 11.53 MB
  unsigned short* udT  = (unsigned short*)w; w += (long)cE * 256 * cF * 2;     // 11.53 MB
  unsigned short* t1   = (unsigned short*)w; w += (long)ROWS * 512 * 2;        // 4.19 MB
  unsigned short* ab   = (unsigned short*)w; w += (long)ROWS * cF * 2;         // 23.07 MB
  unsigned short* t3   = (unsigned short*)w; w += (long)ROWS * 256 * 2;        // 2.10 MB
  float* wt   = (float*)w; w += ROWS * 4;
  float* wrow = (float*)w; w += ROWS * 4;
  int* et  = (int*)w; w += ROWS * 4;
  int* tok = (int*)w; w += ROWS * 4;
  int* cnt = (int*)w; w += cE * 4;
  int* off = (int*)w; w += cE * 4;

  // 1. zero output (atomic-accumulated later)
  k_zero<<<dim3((out_size / 4 + 255) / 256), dim3(256), 0, stream>>>(out, out_size / 4);
  // 2. gating + 3. lists
  k_gating<<<dim3(cT / 256), dim3(256), 0, stream>>>(x, gw, et, wt);
  k_lists<<<dim3(1), dim3(256), 0, stream>>>(et, wt, tok, wrow, cnt, off);
  // 4. folds (fp32 GEMM -> transposed bf16)
  //    b1t[e][r][h]       = (Ug[e] @ Cg)^T : M=H, N=R
  k_fold<<<dim3(cR / 64, cH / 64, cE), dim3(256), 0, stream>>>(
      Ug, (long)cH * cR, cR, Cg, 0, cR, b1t, (long)512 * 1024, 1024, cR);
  //    b1t[e][256+r][h]   = (Uu[e] @ Cu)^T
  k_fold<<<dim3(cR / 64, cH / 64, cE), dim3(256), 0, stream>>>(
      Uu, (long)cH * cR, cR, Cu, 0, cR, b1t + (long)256 * 1024, (long)512 * 1024, 1024, cR);
  //    vd2t[e][h][r]      = (Cd @ Vd[e])^T : M=R, N=H
  k_fold<<<dim3(cH / 64, cR / 64, cE), dim3(256), 0, stream>>>(
      Cd, 0, cR, Vd, (long)cR * cH, cH, vd2t, (long)cH * 256, 256, cR);
  // 5. weight transposes (fp32 -> bf16)
  k_tconv<<<dim3(cF / 32, cR / 32, cE), dim3(256), 0, stream>>>(Vg, vgT, cR, cF);
  k_tconv<<<dim3(cF / 32, cR / 32, cE), dim3(256), 0, stream>>>(Vu, vuT, cR, cF);
  k_tconv<<<dim3(cR / 32, cF / 32, cE), dim3(256), 0, stream>>>(Ud, udT, cF, cR);
  // 6. t1 = gather(x) @ [Ug2 | Uu2]
  k_t1<<<dim3(8, cT / 128, cE), dim3(256), 0, stream>>>(x, b1t, t1, tok, cnt, off);
  // 7. a = silu(t1g @ Vg) * (t1u @ Vu)
  k_act<<<dim3(cF / 64, cT / 128, cE), dim3(256), 0, stream>>>(t1, vgT, vuT, ab, cnt, off);
  // 8. t3 = a @ Ud
  k_t3<<<dim3(cR / 64, cT / 64, cE), dim3(256), 0, stream>>>(ab, udT, t3, cnt, off);
  // 9. out[tok] += w * (t3 @ Vd2)
  k_y<<<dim3(cH / 64, cT / 128, cE), dim3(256), 0, stream>>>(t3, vd2t, out, tok, wrow, cnt, off);
}

// Round 3
// 552.244 us; speedup vs baseline: 1.7816x; 1.1786x over previous
//
#include <hip/hip_runtime.h>
#include <math.h>

constexpr int cE = 8;
constexpr int cH = 1024;
constexpr int cF = 2816;
constexpr int cR = 256;
constexpr int cT = 2048;
constexpr int ROWS = cT * 2;   // total routed (token, expert) rows = T*K
constexpr int LDA = 40;        // padded LDS row stride (BK=32 kernels)
constexpr int LDK = 72;        // padded LDS row stride (BK=64 kernels)

using short8  = __attribute__((ext_vector_type(8))) short;
using float4v = __attribute__((ext_vector_type(4))) float;
#define MFMA16 __builtin_amdgcn_mfma_f32_16x16x32_bf16

__device__ __forceinline__ unsigned short f2bf(float f) {
  union { float f; unsigned u; } v; v.f = f;
  unsigned r = v.u + 0x7fffu + ((v.u >> 16) & 1u);   // RNE
  return (unsigned short)(r >> 16);
}

// pack 8 fp32 -> 8 bf16, single 16B store
__device__ __forceinline__ void store_bf8(unsigned short* dst, float4 a, float4 b) {
  union { unsigned short u[8]; uint4 v; } t;
  t.u[0] = f2bf(a.x); t.u[1] = f2bf(a.y); t.u[2] = f2bf(a.z); t.u[3] = f2bf(a.w);
  t.u[4] = f2bf(b.x); t.u[5] = f2bf(b.y); t.u[6] = f2bf(b.z); t.u[7] = f2bf(b.w);
  *reinterpret_cast<uint4*>(dst) = t.v;
}

// ---------------------------------------------------------------------------
__global__ __launch_bounds__(256) void k_zero(float* __restrict__ p, int n4)
{
  int i = blockIdx.x * 256 + threadIdx.x;
  if (i < n4) reinterpret_cast<float4*>(p)[i] = make_float4(0.f, 0.f, 0.f, 0.f);
}

// ---------------------------------------------------------------------------
// gating: logits = x @ gate_w, top-2, renormalized weights
// ---------------------------------------------------------------------------
__global__ __launch_bounds__(256) void k_gating(
    const float* __restrict__ x, const float* __restrict__ gw,
    int* __restrict__ et, float* __restrict__ wt)
{
  __shared__ float gws[cH * cE];
  const int tid = threadIdx.x;
  for (int i = tid; i < cH * cE; i += 256) gws[i] = gw[i];
  __syncthreads();
  const int t = blockIdx.x * 256 + tid;
  const float4* xr = reinterpret_cast<const float4*>(x + (long)t * cH);
  float l[cE];
#pragma unroll
  for (int e = 0; e < cE; ++e) l[e] = 0.f;
  for (int h4 = 0; h4 < cH / 4; ++h4) {
    float4 v = xr[h4];
    const float* g0 = &gws[(h4 * 4 + 0) * cE];
    const float* g1 = &gws[(h4 * 4 + 1) * cE];
    const float* g2 = &gws[(h4 * 4 + 2) * cE];
    const float* g3 = &gws[(h4 * 4 + 3) * cE];
#pragma unroll
    for (int e = 0; e < cE; ++e)
      l[e] += v.x * g0[e] + v.y * g1[e] + v.z * g2[e] + v.w * g3[e];
  }
  int i0 = 0; float m0 = l[0];
#pragma unroll
  for (int e = 1; e < cE; ++e) if (l[e] > m0) { m0 = l[e]; i0 = e; }
  int i1 = -1; float m1 = -1e30f;
#pragma unroll
  for (int e = 0; e < cE; ++e) if (e != i0 && l[e] > m1) { m1 = l[e]; i1 = e; }
  float w0 = 1.f / (1.f + expf(m1 - m0));
  et[t * 2 + 0] = i0;  et[t * 2 + 1] = i1;
  wt[t * 2 + 0] = w0;  wt[t * 2 + 1] = 1.f - w0;
}

// ---------------------------------------------------------------------------
// build compact per-expert token lists + inverse map (single block)
// ---------------------------------------------------------------------------
__global__ __launch_bounds__(256) void k_lists(
    const int* __restrict__ et, const float* __restrict__ wt,
    int* __restrict__ tok, float* __restrict__ wrow, int* __restrict__ rowmap,
    int* __restrict__ cnt, int* __restrict__ off)
{
  __shared__ int c[cE], p[cE], o[cE];
  const int tid = threadIdx.x;
  if (tid < cE) { c[tid] = 0; p[tid] = 0; }
  __syncthreads();
  for (int i = tid; i < ROWS; i += 256) atomicAdd(&c[et[i]], 1);
  __syncthreads();
  if (tid == 0) {
    int s = 0;
    for (int e = 0; e < cE; ++e) { o[e] = s; s += c[e]; }
  }
  __syncthreads();
  for (int i = tid; i < ROWS; i += 256) {
    int e = et[i];
    int slot = atomicAdd(&p[e], 1);
    int row = o[e] + slot;
    tok[row] = i >> 1;
    wrow[row] = wt[i];
    rowmap[i] = row;
  }
  if (tid < cE) { cnt[tid] = c[tid]; off[tid] = o[tid]; }
}

// ---------------------------------------------------------------------------
// fp32 64x64 tile GEMM loop (folds only)
// ---------------------------------------------------------------------------
__device__ __forceinline__ void mm_loop(
    const float* __restrict__ arow,
    const float* __restrict__ B, int ldb, int n0, int K,
    float (&acc)[4][4], float (&As)[16][64], float (&Bs)[16][64], int tid)
{
  const int ak = (tid & 3) << 2;
  const int ar = tid >> 2;
  const int bk = tid >> 4;
  const int bn = (tid & 15) << 2;
  const int tx = tid & 15, ty = tid >> 4;
  for (int k0 = 0; k0 < K; k0 += 16) {
    float4 av = *reinterpret_cast<const float4*>(arow + k0 + ak);
    As[ak + 0][ar] = av.x;
    As[ak + 1][ar] = av.y;
    As[ak + 2][ar] = av.z;
    As[ak + 3][ar] = av.w;
    *reinterpret_cast<float4*>(&Bs[bk][bn]) =
        *reinterpret_cast<const float4*>(B + (long)(k0 + bk) * ldb + n0 + bn);
    __syncthreads();
#pragma unroll
    for (int kk = 0; kk < 16; ++kk) {
      float4 a4 = *reinterpret_cast<const float4*>(&As[kk][ty << 2]);
      float4 b4 = *reinterpret_cast<const float4*>(&Bs[kk][tx << 2]);
      acc[0][0] += a4.x * b4.x; acc[0][1] += a4.x * b4.y; acc[0][2] += a4.x * b4.z; acc[0][3] += a4.x * b4.w;
      acc[1][0] += a4.y * b4.x; acc[1][1] += a4.y * b4.y; acc[1][2] += a4.y * b4.z; acc[1][3] += a4.y * b4.w;
      acc[2][0] += a4.z * b4.x; acc[2][1] += a4.z * b4.y; acc[2][2] += a4.z * b4.z; acc[2][3] += a4.z * b4.w;
      acc[3][0] += a4.w * b4.x; acc[3][1] += a4.w * b4.y; acc[3][2] += a4.w * b4.z; acc[3][3] += a4.w * b4.w;
    }
    __syncthreads();
  }
}

// fold: C = A @ B (fp32), stored TRANSPOSED as bf16: Ct[n*ldct + m]
__global__ __launch_bounds__(256) void k_fold(
    const float* __restrict__ A, long sA, int lda,
    const float* __restrict__ B, long sB, int ldb,
    unsigned short* __restrict__ Ct, long sC, int ldct, int K)
{
  __shared__ float As[16][64], Bs[16][64];
  const int e = blockIdx.z;
  A += (long)e * sA; B += (long)e * sB; Ct += (long)e * sC;
  const int m0 = blockIdx.y * 64, n0 = blockIdx.x * 64;
  const int tid = threadIdx.x;
  const float* arow = A + (long)(m0 + (tid >> 2)) * lda;
  float acc[4][4] = {};
  mm_loop(arow, B, ldb, n0, K, acc, As, Bs, tid);
  const int tx = tid & 15, ty = tid >> 4;
#pragma unroll
  for (int i = 0; i < 4; ++i) {
    int m = m0 + (ty << 2) + i;
#pragma unroll
    for (int j = 0; j < 4; ++j) {
      int n = n0 + (tx << 2) + j;
      Ct[(long)n * ldct + m] = f2bf(acc[i][j]);
    }
  }
}

// ---------------------------------------------------------------------------
// transpose + fp32->bf16: in [P][Q] per expert -> out [Q][P] per expert
// ---------------------------------------------------------------------------
__global__ __launch_bounds__(256) void k_tconv(
    const float* __restrict__ in, unsigned short* __restrict__ out, int P, int Q)
{
  __shared__ float tile[32][33];
  const long es = (long)P * Q;
  const int e = blockIdx.z;
  in += e * es; out += e * es;
  const int c0 = blockIdx.x * 32, r0 = blockIdx.y * 32;
  const int tid = threadIdx.x;
  const int r = tid >> 3, c4 = (tid & 7) * 4;
  float4 v = *reinterpret_cast<const float4*>(in + (long)(r0 + r) * Q + c0 + c4);
  tile[r][c4 + 0] = v.x; tile[r][c4 + 1] = v.y;
  tile[r][c4 + 2] = v.z; tile[r][c4 + 3] = v.w;
  __syncthreads();
  const int cc = tid >> 3, rr4 = (tid & 7) * 4;
  ushort4 o;
  o.x = f2bf(tile[rr4 + 0][cc]);
  o.y = f2bf(tile[rr4 + 1][cc]);
  o.z = f2bf(tile[rr4 + 2][cc]);
  o.w = f2bf(tile[rr4 + 3][cc]);
  *reinterpret_cast<ushort4*>(out + (long)(c0 + cc) * P + r0 + rr4) = o;
}

// ---------------------------------------------------------------------------
// DENSE t1 GEMM + scatter epilogue.
// C[2048][4096] = x[2048][1024] @ b1t[4096][1024]^T, but each 128-token x
// 128-n tile only writes rows whose routed expert == this tile's expert,
// into the compact t1[row][512]. Tile 128x128, 4 waves of 64x64, BK=64,
// register-prefetch pipeline. grid = (32, 16), all blocks live (2/CU).
// ---------------------------------------------------------------------------
__global__ __launch_bounds__(256, 2) void k_t1d(
    const float* __restrict__ x, const unsigned short* __restrict__ b1t,
    unsigned short* __restrict__ t1, const int* __restrict__ et,
    const int* __restrict__ rowmap)
{
  __shared__ __align__(16) unsigned short As[128 * LDK];
  __shared__ __align__(16) unsigned short Bs[128 * LDK];
  const int tid = threadIdx.x;
  const int m0 = blockIdx.y * 128;
  const int nb = blockIdx.x;                 // 0..31
  const int sr = tid >> 2, sk16 = (tid & 3) * 16;
  const float* A0 = x + (long)(m0 + sr) * cH + sk16;
  const float* A1 = A0 + (long)64 * cH;
  const unsigned short* B0 = b1t + (long)(nb * 128 + sr) * cH + sk16;
  const unsigned short* B1 = B0 + (long)64 * cH;
  float4 ra0[4], ra1[4];
  uint4  rb0[2], rb1[2];
  auto load_slice = [&](int k0) {
#pragma unroll
    for (int i = 0; i < 4; ++i) {
      ra0[i] = *reinterpret_cast<const float4*>(A0 + k0 + i * 4);
      ra1[i] = *reinterpret_cast<const float4*>(A1 + k0 + i * 4);
    }
#pragma unroll
    for (int i = 0; i < 2; ++i) {
      rb0[i] = *reinterpret_cast<const uint4*>(B0 + k0 + i * 8);
      rb1[i] = *reinterpret_cast<const uint4*>(B1 + k0 + i * 8);
    }
  };
  load_slice(0);
  const int wid = tid >> 6, lane = tid & 63;
  const int wm = (wid >> 1) * 64, wn = (wid & 1) * 64;
  const int fr = lane & 15, fq = lane >> 4;
  float4v zf = {0.f, 0.f, 0.f, 0.f};
  float4v acc[4][4];
#pragma unroll
  for (int i = 0; i < 4; ++i)
#pragma unroll
    for (int j = 0; j < 4; ++j) acc[i][j] = zf;
  for (int k0 = 0; k0 < cH; k0 += 64) {
    store_bf8(&As[sr * LDK + sk16], ra0[0], ra0[1]);
    store_bf8(&As[sr * LDK + sk16 + 8], ra0[2], ra0[3]);
    store_bf8(&As[(sr + 64) * LDK + sk16], ra1[0], ra1[1]);
    store_bf8(&As[(sr + 64) * LDK + sk16 + 8], ra1[2], ra1[3]);
    *reinterpret_cast<uint4*>(&Bs[sr * LDK + sk16]) = rb0[0];
    *reinterpret_cast<uint4*>(&Bs[sr * LDK + sk16 + 8]) = rb0[1];
    *reinterpret_cast<uint4*>(&Bs[(sr + 64) * LDK + sk16]) = rb1[0];
    *reinterpret_cast<uint4*>(&Bs[(sr + 64) * LDK + sk16 + 8]) = rb1[1];
    if (k0 + 64 < cH) load_slice(k0 + 64);   // prefetch overlaps MFMA phase
    __syncthreads();
#pragma unroll
    for (int ks = 0; ks < 2; ++ks) {
      short8 af[4], bf[4];
#pragma unroll
      for (int mi = 0; mi < 4; ++mi)
        af[mi] = *reinterpret_cast<const short8*>(
            &As[(wm + mi * 16 + fr) * LDK + ks * 32 + fq * 8]);
#pragma unroll
      for (int nj = 0; nj < 4; ++nj)
        bf[nj] = *reinterpret_cast<const short8*>(
            &Bs[(wn + nj * 16 + fr) * LDK + ks * 32 + fq * 8]);
#pragma unroll
      for (int mi = 0; mi < 4; ++mi)
#pragma unroll
        for (int nj = 0; nj < 4; ++nj)
          acc[mi][nj] = MFMA16(af[mi], bf[nj], acc[mi][nj], 0, 0, 0);
    }
    __syncthreads();
  }
  // scatter epilogue: expert of this n-tile, column base within expert
  const int e_t = nb >> 2;
  const int colbase = (nb & 3) * 128 + wn;
#pragma unroll
  for (int mi = 0; mi < 4; ++mi)
#pragma unroll
    for (int r = 0; r < 4; ++r) {
      int t = m0 + wm + mi * 16 + fq * 4 + r;
      int crow = -1;
      if (et[2 * t] == e_t) crow = rowmap[2 * t];
      else if (et[2 * t + 1] == e_t) crow = rowmap[2 * t + 1];
      if (crow >= 0) {
#pragma unroll
        for (int nj = 0; nj < 4; ++nj)
          t1[(long)crow * 512 + colbase + nj * 16 + fr] = f2bf(acc[mi][nj][r]);
      }
    }
}

// ---------------------------------------------------------------------------
// dual GEMM: a = silu(t1g @ vgT^T) * (t1u @ vuT^T)  [rows x F], K=256
// tile 128x64, BK=32, register prefetch.  grid = (44, 16, E)
// ---------------------------------------------------------------------------
__global__ __launch_bounds__(256, 3) void k_act(
    const unsigned short* __restrict__ t1,
    const unsigned short* __restrict__ vgT, const unsigned short* __restrict__ vuT,
    unsigned short* __restrict__ a, const int* __restrict__ cnt,
    const int* __restrict__ off)
{
  __shared__ __align__(16) unsigned short Ag[128 * LDA], Au[128 * LDA];
  __shared__ __align__(16) unsigned short Bg[64 * LDA],  Bu[64 * LDA];
  const int e = blockIdx.z, c = cnt[e], o = off[e];
  const int m0 = blockIdx.y * 128;
  if (m0 >= c) return;
  const int n0 = blockIdx.x * 64;
  const int tid = threadIdx.x;
  const int sr = tid >> 2, sk = (tid & 3) * 8;
  const unsigned short* ar0 = (m0 + sr < c)      ? t1 + (long)(o + m0 + sr) * 512 + sk      : nullptr;
  const unsigned short* ar1 = (m0 + 64 + sr < c) ? t1 + (long)(o + m0 + 64 + sr) * 512 + sk : nullptr;
  const unsigned short* Btg = vgT + (long)e * cF * 256 + (long)(n0 + sr) * 256 + sk;
  const unsigned short* Btu = vuT + (long)e * cF * 256 + (long)(n0 + sr) * 256 + sk;
  const uint4 zu = make_uint4(0u, 0u, 0u, 0u);
  uint4 rg0, ru0, rg1, ru1, rbg, rbu;
  auto load_slice = [&](int k0) {
    rg0 = ar0 ? *reinterpret_cast<const uint4*>(ar0 + k0)       : zu;
    ru0 = ar0 ? *reinterpret_cast<const uint4*>(ar0 + 256 + k0) : zu;
    rg1 = ar1 ? *reinterpret_cast<const uint4*>(ar1 + k0)       : zu;
    ru1 = ar1 ? *reinterpret_cast<const uint4*>(ar1 + 256 + k0) : zu;
    rbg = *reinterpret_cast<const uint4*>(Btg + k0);
    rbu = *reinterpret_cast<const uint4*>(Btu + k0);
  };
  load_slice(0);
  const int wid = tid >> 6, lane = tid & 63;
  const int wm = (wid >> 1) * 64, wn = (wid & 1) * 32;
  const int fr = lane & 15, fq = lane >> 4;
  float4v zf = {0.f, 0.f, 0.f, 0.f};
  float4v accg[4][2], accu[4][2];
#pragma unroll
  for (int i = 0; i < 4; ++i) { accg[i][0] = zf; accg[i][1] = zf; accu[i][0] = zf; accu[i][1] = zf; }
  for (int k0 = 0; k0 < 256; k0 += 32) {
    *reinterpret_cast<uint4*>(&Ag[sr * LDA + sk]) = rg0;
    *reinterpret_cast<uint4*>(&Au[sr * LDA + sk]) = ru0;
    *reinterpret_cast<uint4*>(&Ag[(sr + 64) * LDA + sk]) = rg1;
    *reinterpret_cast<uint4*>(&Au[(sr + 64) * LDA + sk]) = ru1;
    *reinterpret_cast<uint4*>(&Bg[sr * LDA + sk]) = rbg;
    *reinterpret_cast<uint4*>(&Bu[sr * LDA + sk]) = rbu;
    if (k0 + 32 < 256) load_slice(k0 + 32);
    __syncthreads();
    short8 ag[4], au[4], bg[2], bu[2];
#pragma unroll
    for (int mi = 0; mi < 4; ++mi) {
      ag[mi] = *reinterpret_cast<const short8*>(&Ag[(wm + mi * 16 + fr) * LDA + fq * 8]);
      au[mi] = *reinterpret_cast<const short8*>(&Au[(wm + mi * 16 + fr) * LDA + fq * 8]);
    }
#pragma unroll
    for (int nj = 0; nj < 2; ++nj) {
      bg[nj] = *reinterpret_cast<const short8*>(&Bg[(wn + nj * 16 + fr) * LDA + fq * 8]);
      bu[nj] = *reinterpret_cast<const short8*>(&Bu[(wn + nj * 16 + fr) * LDA + fq * 8]);
    }
#pragma unroll
    for (int mi = 0; mi < 4; ++mi)
#pragma unroll
      for (int nj = 0; nj < 2; ++nj) {
        accg[mi][nj] = MFMA16(ag[mi], bg[nj], accg[mi][nj], 0, 0, 0);
        accu[mi][nj] = MFMA16(au[mi], bu[nj], accu[mi][nj], 0, 0, 0);
      }
    __syncthreads();
  }
#pragma unroll
  for (int mi = 0; mi < 4; ++mi)
#pragma unroll
    for (int r = 0; r < 4; ++r) {
      int row = m0 + wm + mi * 16 + fq * 4 + r;
      if (row < c) {
#pragma unroll
        for (int nj = 0; nj < 2; ++nj) {
          float g = accg[mi][nj][r];
          float u = accu[mi][nj][r];
          float s = g / (1.f + expf(-g)) * u;
          a[(long)(o + row) * cF + n0 + wn + nj * 16 + fr] = f2bf(s);
        }
      }
    }
}

// ---------------------------------------------------------------------------
// t3f += a @ udT^T (split-K=4, fp32 atomic partials)  [rows x 256], K=2816
// tile 64x64, BK=64, register prefetch. grid = (16, 32, E):
//   blockIdx.x = n_tile(0..3) | ksplit(0..3)<<2
// ---------------------------------------------------------------------------
__global__ __launch_bounds__(256, 4) void k_t3(
    const unsigned short* __restrict__ a, const unsigned short* __restrict__ udT,
    float* __restrict__ t3f, const int* __restrict__ cnt,
    const int* __restrict__ off)
{
  __shared__ __align__(16) unsigned short As[64 * LDK], Bs[64 * LDK];
  const int e = blockIdx.z, c = cnt[e], o = off[e];
  const int m0 = blockIdx.y * 64;
  if (m0 >= c) return;
  const int n0 = (blockIdx.x & 3) * 64;
  const int kbase = (blockIdx.x >> 2) * 704;       // 2816 / 4
  const int tid = threadIdx.x;
  const int sr = tid >> 2, sk16 = (tid & 3) * 16;
  const unsigned short* arow = (m0 + sr < c)
      ? a + (long)(o + m0 + sr) * cF + sk16 : nullptr;
  const unsigned short* brow = udT + (long)e * 256 * cF + (long)(n0 + sr) * cF + sk16;
  const uint4 zu = make_uint4(0u, 0u, 0u, 0u);
  uint4 rA[2], rB[2];
  auto load_slice = [&](int k0) {
    rA[0] = arow ? *reinterpret_cast<const uint4*>(arow + k0)     : zu;
    rA[1] = arow ? *reinterpret_cast<const uint4*>(arow + k0 + 8) : zu;
    rB[0] = *reinterpret_cast<const uint4*>(brow + k0);
    rB[1] = *reinterpret_cast<const uint4*>(brow + k0 + 8);
  };
  load_slice(kbase);
  const int wid = tid >> 6, lane = tid & 63;
  const int wm = (wid >> 1) * 32, wn = (wid & 1) * 32;
  const int fr = lane & 15, fq = lane >> 4;
  float4v zf = {0.f, 0.f, 0.f, 0.f};
  float4v acc[2][2] = {{zf, zf}, {zf, zf}};
  const int kend = kbase + 704;
  for (int k0 = kbase; k0 < kend; k0 += 64) {
    *reinterpret_cast<uint4*>(&As[sr * LDK + sk16]) = rA[0];
    *reinterpret_cast<uint4*>(&As[sr * LDK + sk16 + 8]) = rA[1];
    *reinterpret_cast<uint4*>(&Bs[sr * LDK + sk16]) = rB[0];
    *reinterpret_cast<uint4*>(&Bs[sr * LDK + sk16 + 8]) = rB[1];
    if (k0 + 64 < kend) load_slice(k0 + 64);
    __syncthreads();
#pragma unroll
    for (int ks = 0; ks < 2; ++ks) {
      short8 af[2], bf[2];
#pragma unroll
      for (int mi = 0; mi < 2; ++mi)
        af[mi] = *reinterpret_cast<const short8*>(
            &As[(wm + mi * 16 + fr) * LDK + ks * 32 + fq * 8]);
#pragma unroll
      for (int nj = 0; nj < 2; ++nj)
        bf[nj] = *reinterpret_cast<const short8*>(
            &Bs[(wn + nj * 16 + fr) * LDK + ks * 32 + fq * 8]);
#pragma unroll
      for (int mi = 0; mi < 2; ++mi)
#pragma unroll
        for (int nj = 0; nj < 2; ++nj)
          acc[mi][nj] = MFMA16(af[mi], bf[nj], acc[mi][nj], 0, 0, 0);
    }
    __syncthreads();
  }
#pragma unroll
  for (int mi = 0; mi < 2; ++mi)
#pragma unroll
    for (int r = 0; r < 4; ++r) {
      int row = m0 + wm + mi * 16 + fq * 4 + r;
      if (row < c) {
#pragma unroll
        for (int nj = 0; nj < 2; ++nj)
          atomicAdd(&t3f[(long)(o + row) * 256 + n0 + wn + nj * 16 + fr],
                    acc[mi][nj][r]);
      }
    }
}

// ---------------------------------------------------------------------------
// out[tok] += w * (t3f @ vd2t^T)   [rows x 1024], K = 256
// A is fp32 (split-K partials), converted to bf16 while staging.
// tile 128x64, BK=32, register prefetch. grid = (16, 16, E)
// ---------------------------------------------------------------------------
__global__ __launch_bounds__(256, 3) void k_y(
    const float* __restrict__ t3f, const unsigned short* __restrict__ vd2t,
    float* __restrict__ out, const int* __restrict__ tok,
    const float* __restrict__ wrow, const int* __restrict__ cnt,
    const int* __restrict__ off)
{
  __shared__ __align__(16) unsigned short As[128 * LDA], Bs[64 * LDA];
  const int e = blockIdx.z, c = cnt[e], o = off[e];
  const int m0 = blockIdx.y * 128;
  if (m0 >= c) return;
  const int n0 = blockIdx.x * 64;
  const int tid = threadIdx.x;
  const int sr = tid >> 2, sk = (tid & 3) * 8;
  const float* ar0 = (m0 + sr < c)      ? t3f + (long)(o + m0 + sr) * 256 + sk      : nullptr;
  const float* ar1 = (m0 + 64 + sr < c) ? t3f + (long)(o + m0 + 64 + sr) * 256 + sk : nullptr;
  const unsigned short* brow = vd2t + (long)e * cH * 256 + (long)(n0 + sr) * 256 + sk;
  const float4 z4 = make_float4(0.f, 0.f, 0.f, 0.f);
  float4 rA0[2], rA1[2];
  uint4 rB;
  auto load_slice = [&](int k0) {
    rA0[0] = ar0 ? *reinterpret_cast<const float4*>(ar0 + k0)     : z4;
    rA0[1] = ar0 ? *reinterpret_cast<const float4*>(ar0 + k0 + 4) : z4;
    rA1[0] = ar1 ? *reinterpret_cast<const float4*>(ar1 + k0)     : z4;
    rA1[1] = ar1 ? *reinterpret_cast<const float4*>(ar1 + k0 + 4) : z4;
    rB = *reinterpret_cast<const uint4*>(brow + k0);
  };
  load_slice(0);
  const int wid = tid >> 6, lane = tid & 63;
  const int wm = (wid >> 1) * 64, wn = (wid & 1) * 32;
  const int fr = lane & 15, fq = lane >> 4;
  float4v zf = {0.f, 0.f, 0.f, 0.f};
  float4v acc[4][2];
#pragma unroll
  for (int i = 0; i < 4; ++i) { acc[i][0] = zf; acc[i][1] = zf; }
  for (int k0 = 0; k0 < 256; k0 += 32) {
    store_bf8(&As[sr * LDA + sk], rA0[0], rA0[1]);
    store_bf8(&As[(sr + 64) * LDA + sk], rA1[0], rA1[1]);
    *reinterpret_cast<uint4*>(&Bs[sr * LDA + sk]) = rB;
    if (k0 + 32 < 256) load_slice(k0 + 32);
    __syncthreads();
    short8 af[4], bf[2];
#pragma unroll
    for (int mi = 0; mi < 4; ++mi)
      af[mi] = *reinterpret_cast<const short8*>(&As[(wm + mi * 16 + fr) * LDA + fq * 8]);
#pragma unroll
    for (int nj = 0; nj < 2; ++nj)
      bf[nj] = *reinterpret_cast<const short8*>(&Bs[(wn + nj * 16 + fr) * LDA + fq * 8]);
#pragma unroll
    for (int mi = 0; mi < 4; ++mi)
#pragma unroll
      for (int nj = 0; nj < 2; ++nj)
        acc[mi][nj] = MFMA16(af[mi], bf[nj], acc[mi][nj], 0, 0, 0);
    __syncthreads();
  }
#pragma unroll
  for (int mi = 0; mi < 4; ++mi)
#pragma unroll
    for (int r = 0; r < 4; ++r) {
      int row = m0 + wm + mi * 16 + fq * 4 + r;
      if (row < c) {
        int t = tok[o + row];
        float w = wrow[o + row];
        float* dst = out + (long)t * cH + n0 + wn;
#pragma unroll
        for (int nj = 0; nj < 2; ++nj)
          atomicAdd(dst + nj * 16 + fr, w * acc[mi][nj][r]);
      }
    }
}

// ---------------------------------------------------------------------------
extern "C" void kernel_launch(void* const* d_in, const int* in_sizes, int n_in,
                              void* d_out, int out_size, void* d_ws, size_t ws_size,
                              hipStream_t stream)
{
  const float* x  = (const float*)d_in[0];
  const float* gw = (const float*)d_in[1];
  const float* Ug = (const float*)d_in[2];
  const float* Cg = (const float*)d_in[3];
  const float* Vg = (const float*)d_in[4];
  const float* Cu = (const float*)d_in[6];
  const float* Uu = (const float*)d_in[5];
  const float* Vu = (const float*)d_in[7];
  const float* Ud = (const float*)d_in[8];
  const float* Cd = (const float*)d_in[9];
  const float* Vd = (const float*)d_in[10];
  float* out = (float*)d_out;

  // workspace layout: ~79 MiB
  char* w = (char*)d_ws;
  unsigned short* b1t  = (unsigned short*)w; w += (long)cE * 512 * 1024 * 2;   // 8.39 MB
  unsigned short* vd2t = (unsigned short*)w; w += (long)cE * cH * 256 * 2;     // 4.19 MB
  unsigned short* vgT  = (unsigned short*)w; w += (long)cE * cF * 256 * 2;     // 11.53 MB
  unsigned short* vuT  = (unsigned short*)w; w += (long)cE * cF * 256 * 2;     // 11.53 MB
  unsigned short* udT  = (unsigned short*)w; w += (long)cE * 256 * cF * 2;     // 11.53 MB
  unsigned short* t1   = (unsigned short*)w; w += (long)ROWS * 512 * 2;        // 4.19 MB
  unsigned short* ab   = (unsigned short*)w; w += (long)ROWS * cF * 2;         // 23.07 MB
  float* t3f = (float*)w; w += (long)ROWS * 256 * 4;                           // 4.19 MB
  float* wt     = (float*)w; w += ROWS * 4;
  float* wrow   = (float*)w; w += ROWS * 4;
  int* et     = (int*)w; w += ROWS * 4;
  int* tok    = (int*)w; w += ROWS * 4;
  int* rowmap = (int*)w; w += ROWS * 4;
  int* cnt = (int*)w; w += cE * 4;
  int* off = (int*)w; w += cE * 4;

  // 1. zero accumulators (harness poisons everything with 0xAA)
  k_zero<<<dim3((out_size / 4 + 255) / 256), dim3(256), 0, stream>>>(out, out_size / 4);
  k_zero<<<dim3((ROWS * 256 / 4 + 255) / 256), dim3(256), 0, stream>>>(t3f, ROWS * 256 / 4);
  // 2. gating + lists
  k_gating<<<dim3(cT / 256), dim3(256), 0, stream>>>(x, gw, et, wt);
  k_lists<<<dim3(1), dim3(256), 0, stream>>>(et, wt, tok, wrow, rowmap, cnt, off);
  // 3. folds (fp32 GEMM -> transposed bf16)
  k_fold<<<dim3(cR / 64, cH / 64, cE), dim3(256), 0, stream>>>(
      Ug, (long)cH * cR, cR, Cg, 0, cR, b1t, (long)512 * 1024, 1024, cR);
  k_fold<<<dim3(cR / 64, cH / 64, cE), dim3(256), 0, stream>>>(
      Uu, (long)cH * cR, cR, Cu, 0, cR, b1t + (long)256 * 1024, (long)512 * 1024, 1024, cR);
  k_fold<<<dim3(cH / 64, cR / 64, cE), dim3(256), 0, stream>>>(
      Cd, 0, cR, Vd, (long)cR * cH, cH, vd2t, (long)cH * 256, 256, cR);
  // 4. weight transposes (fp32 -> bf16)
  k_tconv<<<dim3(cF / 32, cR / 32, cE), dim3(256), 0, stream>>>(Vg, vgT, cR, cF);
  k_tconv<<<dim3(cF / 32, cR / 32, cE), dim3(256), 0, stream>>>(Vu, vuT, cR, cF);
  k_tconv<<<dim3(cR / 32, cF / 32, cE), dim3(256), 0, stream>>>(Ud, udT, cF, cR);
  // 5. dense t1 GEMM + scatter into compact rows
  k_t1d<<<dim3(32, cT / 128), dim3(256), 0, stream>>>(x, b1t, t1, et, rowmap);
  // 6. a = silu(t1g @ Vg) * (t1u @ Vu)
  k_act<<<dim3(cF / 64, cT / 128, cE), dim3(256), 0, stream>>>(t1, vgT, vuT, ab, cnt, off);
  // 7. t3f = a @ Ud (split-K=4, fp32 atomics)
  k_t3<<<dim3(16, cT / 64, cE), dim3(256), 0, stream>>>(ab, udT, t3f, cnt, off);
  // 8. out[tok] += w * (t3f @ Vd2)
  k_y<<<dim3(cH / 64, cT / 128, cE), dim3(256), 0, stream>>>(t3f, vd2t, out, tok, wrow, cnt, off);
}